// Round 4
// baseline (389.023 us; speedup 1.0000x reference)
//
#include <hip/hip_runtime.h>
#include <math.h>

#define N_NODES 50000
#define DEG 16
#define IN_F 256
#define NH 4
#define OUT_F 64
#define HF 256          // NH * OUT_F
#define NEG_SLOPE 0.2f

typedef float  floatx4 __attribute__((ext_vector_type(4)));
typedef short  short8  __attribute__((ext_vector_type(8)));

__device__ __forceinline__ ushort f2bf(float x) {   // RNE fp32->bf16
    unsigned u = __float_as_uint(x);
    u = (u + 0x7FFFu + ((u >> 16) & 1u)) >> 16;
    return (ushort)u;
}
__device__ __forceinline__ float bf2f(ushort b) {
    return __uint_as_float(((unsigned)b) << 16);
}
__device__ __forceinline__ void gld16(const void* g, void* l) {
    __builtin_amdgcn_global_load_lds((const __attribute__((address_space(1))) void*)g,
                                     (__attribute__((address_space(3))) void*)l, 16, 0, 0);
}

#define STAGE_A8(dst, v0, v1) do { short8 a8_;                        \
    a8_[0] = (short)f2bf((v0).x); a8_[1] = (short)f2bf((v0).y);       \
    a8_[2] = (short)f2bf((v0).z); a8_[3] = (short)f2bf((v0).w);       \
    a8_[4] = (short)f2bf((v1).x); a8_[5] = (short)f2bf((v1).y);       \
    a8_[6] = (short)f2bf((v1).z); a8_[7] = (short)f2bf((v1).w);       \
    *(short8*)(dst) = a8_; } while (0)

// ---- W[256,256] fp32 -> Wt[n][k] bf16 (transposed) ----
__global__ __launch_bounds__(256) void cast_wt_kernel(const float* __restrict__ W,
                                                      ushort* __restrict__ Wt) {
    __shared__ float tile[64][65];
    const int bx = blockIdx.x & 3;    // n tile
    const int by = blockIdx.x >> 2;   // k tile
#pragma unroll
    for (int i = 0; i < 16; ++i) {
        int idx = threadIdx.x + 256 * i;
        int r = idx >> 6, c = idx & 63;
        tile[r][c] = W[(by * 64 + r) * 256 + bx * 64 + c];
    }
    __syncthreads();
#pragma unroll
    for (int i = 0; i < 16; ++i) {
        int idx = threadIdx.x + 256 * i;
        int n = idx >> 6, k = idx & 63;
        Wt[(size_t)(bx * 64 + n) * 256 + by * 64 + k] = f2bf(tile[k][n]);
    }
}

// ---- MFMA GEMM, full-N single pass, double-buffered LDS (unchanged) ----
__global__ __launch_bounds__(256) void mfma_gemm_kernel(const float* __restrict__ A,
                                                        const ushort* __restrict__ Bt,
                                                        const float* __restrict__ attn_l,
                                                        const float* __restrict__ attn_r,
                                                        ushort* __restrict__ H,
                                                        float* __restrict__ arow_g,
                                                        float* __restrict__ acol_g,
                                                        int M) {
    __shared__ __align__(16) ushort smem[20480];
    ushort* Ab[2] = { smem,         smem + 10240 };
    ushort* Bb[2] = { smem + 2048,  smem + 12288 };

    const int tid  = threadIdx.x;
    const int w    = tid >> 6;
    const int lane = tid & 63;
    const int wm   = w >> 1, wn = w & 1;
    const int g    = lane >> 4;
    const int r    = lane & 15;

    const int m0 = blockIdx.x * 64;

    const int srow = tid >> 2;
    const int kc8  = (tid & 3) * 8;
    const int gmA  = min(m0 + srow, M - 1);
    const float*  Aptr = A  + (size_t)gmA  * 256 + kc8;
    const ushort* Bptr = Bt + (size_t)srow * 256 + kc8;

    floatx4 acc[2][8];
#pragma unroll
    for (int i = 0; i < 2; ++i)
#pragma unroll
        for (int j = 0; j < 8; ++j) acc[i][j] = (floatx4)(0.f);

    {
        float4 t0 = *(const float4*)(Aptr);
        float4 t1 = *(const float4*)(Aptr + 4);
        STAGE_A8(Ab[0] + tid * 8, t0, t1);
        gld16(Bptr,             Bb[0] +        tid * 8);
        gld16(Bptr +  64 * 256, Bb[0] + 2048 + tid * 8);
        gld16(Bptr + 128 * 256, Bb[0] + 4096 + tid * 8);
        gld16(Bptr + 192 * 256, Bb[0] + 6144 + tid * 8);
    }
    float4 qx[2], qy[2];
    qx[1] = *(const float4*)(Aptr + 32);  qy[1] = *(const float4*)(Aptr + 36);
    qx[0] = *(const float4*)(Aptr + 64);  qy[0] = *(const float4*)(Aptr + 68);
    __syncthreads();

#pragma unroll
    for (int kk = 0; kk < 8; ++kk) {
        ushort* Ac = Ab[kk & 1];
        ushort* Bc = Bb[kk & 1];
        if (kk < 7) {
            const int nb = (kk + 1) & 1;
            STAGE_A8(Ab[nb] + tid * 8, qx[nb], qy[nb]);
            const ushort* bsrc = Bptr + (kk + 1) * 32;
            gld16(bsrc,             Bb[nb] +        tid * 8);
            gld16(bsrc +  64 * 256, Bb[nb] + 2048 + tid * 8);
            gld16(bsrc + 128 * 256, Bb[nb] + 4096 + tid * 8);
            gld16(bsrc + 192 * 256, Bb[nb] + 6144 + tid * 8);
        }
        if (kk < 5) {
            const int lb = (kk + 3) & 1;
            qx[lb] = *(const float4*)(Aptr + (kk + 3) * 32);
            qy[lb] = *(const float4*)(Aptr + (kk + 3) * 32 + 4);
        }

        short8 af[2], bfr[8];
#pragma unroll
        for (int i = 0; i < 2; ++i)
            af[i] = *(const short8*)&Ac[(size_t)(wm * 32 + i * 16 + r) * 32 + g * 8];
#pragma unroll
        for (int j = 0; j < 8; ++j)
            bfr[j] = *(const short8*)&Bc[(size_t)(wn * 128 + j * 16 + r) * 32 + g * 8];
#pragma unroll
        for (int i = 0; i < 2; ++i)
#pragma unroll
            for (int j = 0; j < 8; ++j)
                acc[i][j] = __builtin_amdgcn_mfma_f32_16x16x32_bf16(af[i], bfr[j], acc[i][j], 0, 0, 0);

        __syncthreads();
    }

    float* wreg = (float*)smem + w * 1024;
    const int rr = lane >> 2;
    const int cb = (lane & 3) * 16;

#pragma unroll
    for (int h = 0; h < 2; ++h) {
        const int head = wn * 2 + h;
        float al[16], ar[16];
#pragma unroll
        for (int q = 0; q < 4; ++q) {
            *(float4*)&al[q * 4] = *(const float4*)(attn_l + head * 64 + cb + q * 4);
            *(float4*)&ar[q * 4] = *(const float4*)(attn_r + head * 64 + cb + q * 4);
        }
#pragma unroll
        for (int i = 0; i < 2; ++i) {
#pragma unroll
            for (int j = 0; j < 4; ++j)
#pragma unroll
                for (int reg = 0; reg < 4; ++reg)
                    wreg[(g * 4 + reg) * 64 + j * 16 + r] = acc[i][h * 4 + j][reg];

            float v[16];
#pragma unroll
            for (int q = 0; q < 4; ++q)
                *(float4*)&v[q * 4] = *(const float4*)&wreg[rr * 64 + cb + q * 4];

            float pl = 0.f, pr = 0.f;
#pragma unroll
            for (int k = 0; k < 16; ++k) { pl += v[k] * al[k]; pr += v[k] * ar[k]; }
            pl += __shfl_xor(pl, 1); pl += __shfl_xor(pl, 2);
            pr += __shfl_xor(pr, 1); pr += __shfl_xor(pr, 2);

            const int gm = m0 + wm * 32 + i * 16 + rr;
            if (gm < M) {
                short8 h0, h1;
#pragma unroll
                for (int k = 0; k < 8; ++k) { h0[k] = (short)f2bf(v[k]); h1[k] = (short)f2bf(v[8 + k]); }
                ushort* dst = H + (size_t)gm * 256 + wn * 128 + h * 64 + cb;
                *(short8*)dst       = h0;
                *(short8*)(dst + 8) = h1;
                if ((lane & 3) == 0) {
                    arow_g[gm * NH + head] = pl;
                    acol_g[gm * NH + head] = pr;
                }
            }
        }
    }
}

// ---- feature-sliced softmax+aggregate ----
// slice s = blockIdx&7 -> XCD s (round-robin heuristic): XCD s only touches
// H[:, 32s:32s+32] (3.2 MB, fits its 4 MiB L2) => kills the 8x cross-XCD
// compulsory duplication (196 MB -> ~slice fills).  Softmax (head s>>1)
// recomputed per slice.  Per wave: 64 dsts, 8 groups of 8, 3-stage pipeline:
//   A(g): ci loads (8 vm)   B(g): gld16 hv -> LDS + acol + arow   C(g): consume
// Hand-counted vmcnt (min-vector-set counts: A=8, B=16, C=8 stores); all
// loads clamped + stores unconditional (addr-select to scratch) so counts
// are identical in tail blocks.  No __syncthreads (wave-private LDS).
__global__ __launch_bounds__(256, 2) void agg_kernel(const int* __restrict__ col_ind,
                                                     const ushort* __restrict__ H,
                                                     const float* __restrict__ arow_g,
                                                     const float* __restrict__ acol_g,
                                                     float* __restrict__ out,
                                                     float* __restrict__ scratch) {
    __shared__ __align__(16) ushort lds[4][2][4096];   // per wave: 2 bufs x 8 KB
    const int wave = threadIdx.x >> 6, lane = threadIdx.x & 63;
    const int s    = blockIdx.x & 7;          // feature slice
    const int head = s >> 1;
    const int dstbase = (blockIdx.x >> 3) * 256 + wave * 64;
    const int e = lane >> 2, q = lane & 3;    // edge, 16B quarter

    const ushort* Hs = H + s * 32 + q * 8;    // + src*256 per edge

    int   ci[3][8];
    float ac[2][8], arw[2][8];

#define SB __builtin_amdgcn_sched_barrier(0)

#define PH_A(g) { _Pragma("unroll") for (int d = 0; d < 8; ++d) {              \
        int dd = dstbase + (g) * 8 + d; dd = dd < N_NODES ? dd : N_NODES - 1;  \
        ci[(g) % 3][d] = col_ind[dd * DEG + e]; } }

#define PH_B(g) { _Pragma("unroll") for (int d = 0; d < 8; ++d) {              \
        int sc = ci[(g) % 3][d];                                               \
        sc = sc < 0 ? 0 : (sc >= N_NODES ? N_NODES - 1 : sc);                  \
        gld16(Hs + (size_t)sc * 256, &lds[wave][(g) & 1][d * 512 + lane * 8]); \
        ac[(g) & 1][d] = acol_g[sc * NH + head];                               \
        int dd = dstbase + (g) * 8 + d; dd = dd < N_NODES ? dd : N_NODES - 1;  \
        arw[(g) & 1][d] = arow_g[dd * NH + head]; } }

#define PH_C(g) { _Pragma("unroll") for (int d = 0; d < 8; ++d) {              \
        float sv = arw[(g) & 1][d] + ac[(g) & 1][d];                           \
        sv = sv >= 0.f ? sv : NEG_SLOPE * sv;                                  \
        float mx = sv;                                                         \
        mx = fmaxf(mx, __shfl_xor(mx, 4));  mx = fmaxf(mx, __shfl_xor(mx, 8)); \
        mx = fmaxf(mx, __shfl_xor(mx, 16)); mx = fmaxf(mx, __shfl_xor(mx, 32));\
        float ex = __expf(sv - mx);                                            \
        float su = ex;                                                         \
        su += __shfl_xor(su, 4);  su += __shfl_xor(su, 8);                     \
        su += __shfl_xor(su, 16); su += __shfl_xor(su, 32);                    \
        short8 hv = *(const short8*)&lds[wave][(g) & 1][d * 512 + lane * 8];   \
        float t[8];                                                            \
        _Pragma("unroll") for (int k = 0; k < 8; ++k)                          \
            t[k] = ex * bf2f((ushort)hv[k]);                                   \
        _Pragma("unroll") for (int k = 0; k < 8; ++k) {                        \
            t[k] += __shfl_xor(t[k], 4);  t[k] += __shfl_xor(t[k], 8);         \
            t[k] += __shfl_xor(t[k], 16); t[k] += __shfl_xor(t[k], 32); }      \
        if (lane < 8) {                                                        \
            const int dd = dstbase + (g) * 8 + d;                              \
            const int half = lane >> 2;                                        \
            const float inv = 1.f / su;                                        \
            float4 o = make_float4(t[half * 4] * inv,     t[half * 4 + 1] * inv, \
                                   t[half * 4 + 2] * inv, t[half * 4 + 3] * inv); \
            float* p = (dd < N_NODES)                                          \
                ? out + (size_t)dd * 256 + s * 32 + q * 8 + half * 4           \
                : scratch + threadIdx.x * 4;                                   \
            *(float4*)p = o; } } }

    // prologue: A0 A1 | wait A0 | B0
    SB; PH_A(0); PH_A(1); SB;
    asm volatile("s_waitcnt vmcnt(8)" ::: "memory"); SB;
    PH_B(0); SB;

#pragma unroll
    for (int g = 0; g < 8; ++g) {
        if (g < 6) { PH_A(g + 2); }
        SB;
        if (g < 7) {
            // wait: ci(g+1) complete (min-vector newer: g==0 ->24, 1..5 ->32, 6 ->24)
            if (g == 0)      { asm volatile("s_waitcnt vmcnt(24)" ::: "memory"); }
            else if (g <= 5) { asm volatile("s_waitcnt vmcnt(32)" ::: "memory"); }
            else             { asm volatile("s_waitcnt vmcnt(24)" ::: "memory"); }
            SB;
            PH_B(g + 1);
            SB;
        }
        // wait: hv(g) landed in LDS (min-vector newer: 0->24, 1..5->32, 6->24, 7->8)
        if (g == 0)      { asm volatile("s_waitcnt vmcnt(24)" ::: "memory"); }
        else if (g <= 5) { asm volatile("s_waitcnt vmcnt(32)" ::: "memory"); }
        else if (g == 6) { asm volatile("s_waitcnt vmcnt(24)" ::: "memory"); }
        else             { asm volatile("s_waitcnt vmcnt(8)"  ::: "memory"); }
        SB;
        PH_C(g);
        SB;
    }
#undef PH_A
#undef PH_B
#undef PH_C
#undef SB
}

extern "C" void kernel_launch(void* const* d_in, const int* in_sizes, int n_in,
                              void* d_out, int out_size, void* d_ws, size_t ws_size,
                              hipStream_t stream) {
    const int*   col_ind = (const int*)d_in[1];
    const float* feat    = (const float*)d_in[4];
    const float* W       = (const float*)d_in[5];
    const float* attn_l  = (const float*)d_in[6];
    const float* attn_r  = (const float*)d_in[7];
    float* out = (float*)d_out;

    // ws: Wt 128KB | h_bf 25.6MB | arow 0.8MB | acol 0.8MB
    ushort* Wt   = (ushort*)d_ws;
    ushort* h_bf = Wt + 256 * 256;
    float*  arow = (float*)(h_bf + (size_t)N_NODES * HF);
    float*  acol = arow + (size_t)N_NODES * NH;

    const size_t need = (256 * 256 + (size_t)N_NODES * HF) * 2
                      + (size_t)N_NODES * NH * 4 * 2;
    if (ws_size < need) return;

    cast_wt_kernel<<<16, 256, 0, stream>>>(W, Wt);

    mfma_gemm_kernel<<<(N_NODES + 63) / 64, 256, 0, stream>>>(feat, Wt, attn_l, attn_r,
                                                              h_bf, arow, acol, N_NODES);

    // 8 slices x ceil(N/256) dst-groups; slice = blockIdx & 7 -> XCD (heuristic)
    const int dst_groups = (N_NODES + 255) / 256;
    agg_kernel<<<8 * dst_groups, 256, 0, stream>>>(col_ind, h_bf, arow, acol, out,
                                                   (float*)Wt /*scratch dump*/);
}

// Round 5
// 191.137 us; speedup vs baseline: 2.0353x; 2.0353x over previous
//
#include <hip/hip_runtime.h>
#include <math.h>

#define N_NODES 50000
#define DEG 16
#define IN_F 256
#define NH 4
#define OUT_F 64
#define HF 256          // NH * OUT_F
#define NEG_SLOPE 0.2f

typedef float  floatx4 __attribute__((ext_vector_type(4)));
typedef short  short8  __attribute__((ext_vector_type(8)));

__device__ __forceinline__ ushort f2bf(float x) {   // RNE fp32->bf16
    unsigned u = __float_as_uint(x);
    u = (u + 0x7FFFu + ((u >> 16) & 1u)) >> 16;
    return (ushort)u;
}
__device__ __forceinline__ float bf2f(ushort b) {
    return __uint_as_float(((unsigned)b) << 16);
}
__device__ __forceinline__ void gld16(const void* g, void* l) {
    __builtin_amdgcn_global_load_lds((const __attribute__((address_space(1))) void*)g,
                                     (__attribute__((address_space(3))) void*)l, 16, 0, 0);
}

#define STAGE_A8(dst, v0, v1) do { short8 a8_;                        \
    a8_[0] = (short)f2bf((v0).x); a8_[1] = (short)f2bf((v0).y);       \
    a8_[2] = (short)f2bf((v0).z); a8_[3] = (short)f2bf((v0).w);       \
    a8_[4] = (short)f2bf((v1).x); a8_[5] = (short)f2bf((v1).y);       \
    a8_[6] = (short)f2bf((v1).z); a8_[7] = (short)f2bf((v1).w);       \
    *(short8*)(dst) = a8_; } while (0)

// ---- W[256,256] fp32 -> Wt[n][k] bf16 (transposed) ----
__global__ __launch_bounds__(256) void cast_wt_kernel(const float* __restrict__ W,
                                                      ushort* __restrict__ Wt) {
    __shared__ float tile[64][65];
    const int bx = blockIdx.x & 3;    // n tile
    const int by = blockIdx.x >> 2;   // k tile
#pragma unroll
    for (int i = 0; i < 16; ++i) {
        int idx = threadIdx.x + 256 * i;
        int r = idx >> 6, c = idx & 63;
        tile[r][c] = W[(by * 64 + r) * 256 + bx * 64 + c];
    }
    __syncthreads();
#pragma unroll
    for (int i = 0; i < 16; ++i) {
        int idx = threadIdx.x + 256 * i;
        int n = idx >> 6, k = idx & 63;
        Wt[(size_t)(bx * 64 + n) * 256 + by * 64 + k] = f2bf(tile[k][n]);
    }
}

// ---- MFMA GEMM, full-N single pass, double-buffered LDS (R3 version) ----
__global__ __launch_bounds__(256) void mfma_gemm_kernel(const float* __restrict__ A,
                                                        const ushort* __restrict__ Bt,
                                                        const float* __restrict__ attn_l,
                                                        const float* __restrict__ attn_r,
                                                        ushort* __restrict__ H,
                                                        float* __restrict__ arow_g,
                                                        float* __restrict__ acol_g,
                                                        int M) {
    __shared__ __align__(16) ushort smem[20480];
    ushort* Ab[2] = { smem,         smem + 10240 };
    ushort* Bb[2] = { smem + 2048,  smem + 12288 };

    const int tid  = threadIdx.x;
    const int w    = tid >> 6;
    const int lane = tid & 63;
    const int wm   = w >> 1, wn = w & 1;
    const int g    = lane >> 4;
    const int r    = lane & 15;

    const int m0 = blockIdx.x * 64;

    const int srow = tid >> 2;
    const int kc8  = (tid & 3) * 8;
    const int gmA  = min(m0 + srow, M - 1);
    const float*  Aptr = A  + (size_t)gmA  * 256 + kc8;
    const ushort* Bptr = Bt + (size_t)srow * 256 + kc8;

    floatx4 acc[2][8];
#pragma unroll
    for (int i = 0; i < 2; ++i)
#pragma unroll
        for (int j = 0; j < 8; ++j) acc[i][j] = (floatx4)(0.f);

    {
        float4 t0 = *(const float4*)(Aptr);
        float4 t1 = *(const float4*)(Aptr + 4);
        STAGE_A8(Ab[0] + tid * 8, t0, t1);
        gld16(Bptr,             Bb[0] +        tid * 8);
        gld16(Bptr +  64 * 256, Bb[0] + 2048 + tid * 8);
        gld16(Bptr + 128 * 256, Bb[0] + 4096 + tid * 8);
        gld16(Bptr + 192 * 256, Bb[0] + 6144 + tid * 8);
    }
    float4 qx[2], qy[2];
    qx[1] = *(const float4*)(Aptr + 32);  qy[1] = *(const float4*)(Aptr + 36);
    qx[0] = *(const float4*)(Aptr + 64);  qy[0] = *(const float4*)(Aptr + 68);
    __syncthreads();

#pragma unroll
    for (int kk = 0; kk < 8; ++kk) {
        ushort* Ac = Ab[kk & 1];
        ushort* Bc = Bb[kk & 1];
        if (kk < 7) {
            const int nb = (kk + 1) & 1;
            STAGE_A8(Ab[nb] + tid * 8, qx[nb], qy[nb]);
            const ushort* bsrc = Bptr + (kk + 1) * 32;
            gld16(bsrc,             Bb[nb] +        tid * 8);
            gld16(bsrc +  64 * 256, Bb[nb] + 2048 + tid * 8);
            gld16(bsrc + 128 * 256, Bb[nb] + 4096 + tid * 8);
            gld16(bsrc + 192 * 256, Bb[nb] + 6144 + tid * 8);
        }
        if (kk < 5) {
            const int lb = (kk + 3) & 1;
            qx[lb] = *(const float4*)(Aptr + (kk + 3) * 32);
            qy[lb] = *(const float4*)(Aptr + (kk + 3) * 32 + 4);
        }

        short8 af[2], bfr[8];
#pragma unroll
        for (int i = 0; i < 2; ++i)
            af[i] = *(const short8*)&Ac[(size_t)(wm * 32 + i * 16 + r) * 32 + g * 8];
#pragma unroll
        for (int j = 0; j < 8; ++j)
            bfr[j] = *(const short8*)&Bc[(size_t)(wn * 128 + j * 16 + r) * 32 + g * 8];
#pragma unroll
        for (int i = 0; i < 2; ++i)
#pragma unroll
            for (int j = 0; j < 8; ++j)
                acc[i][j] = __builtin_amdgcn_mfma_f32_16x16x32_bf16(af[i], bfr[j], acc[i][j], 0, 0, 0);

        __syncthreads();
    }

    float* wreg = (float*)smem + w * 1024;
    const int rr = lane >> 2;
    const int cb = (lane & 3) * 16;

#pragma unroll
    for (int h = 0; h < 2; ++h) {
        const int head = wn * 2 + h;
        float al[16], ar[16];
#pragma unroll
        for (int q = 0; q < 4; ++q) {
            *(float4*)&al[q * 4] = *(const float4*)(attn_l + head * 64 + cb + q * 4);
            *(float4*)&ar[q * 4] = *(const float4*)(attn_r + head * 64 + cb + q * 4);
        }
#pragma unroll
        for (int i = 0; i < 2; ++i) {
#pragma unroll
            for (int j = 0; j < 4; ++j)
#pragma unroll
                for (int reg = 0; reg < 4; ++reg)
                    wreg[(g * 4 + reg) * 64 + j * 16 + r] = acc[i][h * 4 + j][reg];

            float v[16];
#pragma unroll
            for (int q = 0; q < 4; ++q)
                *(float4*)&v[q * 4] = *(const float4*)&wreg[rr * 64 + cb + q * 4];

            float pl = 0.f, pr = 0.f;
#pragma unroll
            for (int k = 0; k < 16; ++k) { pl += v[k] * al[k]; pr += v[k] * ar[k]; }
            pl += __shfl_xor(pl, 1); pl += __shfl_xor(pl, 2);
            pr += __shfl_xor(pr, 1); pr += __shfl_xor(pr, 2);

            const int gm = m0 + wm * 32 + i * 16 + rr;
            if (gm < M) {
                short8 h0, h1;
#pragma unroll
                for (int k = 0; k < 8; ++k) { h0[k] = (short)f2bf(v[k]); h1[k] = (short)f2bf(v[8 + k]); }
                ushort* dst = H + (size_t)gm * 256 + wn * 128 + h * 64 + cb;
                *(short8*)dst       = h0;
                *(short8*)(dst + 8) = h1;
                if ((lane & 3) == 0) {
                    arow_g[gm * NH + head] = pl;
                    acol_g[gm * NH + head] = pr;
                }
            }
        }
    }
}

// ---- fused softmax+aggregate: 1 dst/wave, 4 rotating 1KB LDS slots ----
// LDS: 4 KB/wave -> 16 KB/block -> 8 blocks/CU -> 32 waves/CU (vs R3's ~12).
// Pipeline per wave: [ci+score loads] [issue t0..t3] [softmax under flight]
// then rotate: wait vmcnt(3) -> consume slot(t) -> issue t+4 into same slot.
// Slot-reuse safety: consume(t)'s FMAs force the lgkm drain of its ds_read
// BEFORE the next gld16 issue (sched_barrier-fenced), so the incoming LDS
// write cannot pass the pending read.  Wave-private LDS: no __syncthreads.
__global__ __launch_bounds__(256) void agg_kernel(const int* __restrict__ col_ind,
                                                  const ushort* __restrict__ H,
                                                  const float* __restrict__ arow_g,
                                                  const float* __restrict__ acol_g,
                                                  float* __restrict__ out) {
    __shared__ __align__(16) ushort lds[4][2048];   // 4 KB per wave: 4 slots x 1 KB
    const int wave = threadIdx.x >> 6, lane = threadIdx.x & 63;
    const int d0   = blockIdx.x * 4 + wave;
    const int hidx = lane >> 4, e_s = lane & 15;

    int src0 = col_ind[d0 * DEG + e_s];
    src0 = src0 < 0 ? 0 : (src0 >= N_NODES ? N_NODES - 1 : src0);

    // score loads first (older in vm FIFO than all gathers)
    const float sc_r0 = arow_g[d0 * NH + hidx];
    const float sc_c0 = acol_g[src0 * NH + hidx];
    __builtin_amdgcn_sched_barrier(0);

    const int fb     = (lane & 31) * 8;          // feature chunk (8 bf16)
    const int head_a = (lane & 31) >> 3;         // head owning fb
    const int half   = lane >> 5;                // even/odd edge split

    ushort* lbase = &lds[wave][0];

#define ISSUE(t) { const int r_ = __shfl(src0, 2 * (t) + half);                 \
        gld16(H + (size_t)r_ * 256 + fb, lbase + ((t) & 3) * 512 + lane * 8); } \
        __builtin_amdgcn_sched_barrier(0)

#define CONSUME(t) { short8 hv_ = *(const short8*)(lbase + ((t) & 3) * 512 + lane * 8); \
        _Pragma("unroll") for (int k_ = 0; k_ < 8; ++k_)                        \
            acc0[k_] += a0[t] * bf2f((ushort)hv_[k_]); }                        \
        __builtin_amdgcn_sched_barrier(0)

#define WAITV(n) asm volatile("s_waitcnt vmcnt(" #n ")" ::: "memory");          \
        __builtin_amdgcn_sched_barrier(0)

    // ---- issue first 4 gathers (slots 0..3) ----
    ISSUE(0); ISSUE(1); ISSUE(2); ISSUE(3);

    // ---- softmax under the in-flight gathers (compiler waits only the
    //      older score loads: vmcnt(4), leaving gathers outstanding) ----
    float s0 = sc_r0 + sc_c0;
    s0 = (s0 >= 0.f) ? s0 : NEG_SLOPE * s0;
    float m0 = s0;
#pragma unroll
    for (int off = 1; off < 16; off <<= 1)
        m0 = fmaxf(m0, __shfl_xor(m0, off));
    float ex0 = expf(s0 - m0);
    float su0 = ex0;
#pragma unroll
    for (int off = 1; off < 16; off <<= 1)
        su0 += __shfl_xor(su0, off);
    const float alpha0 = ex0 / su0;

    float a0[8];
#pragma unroll
    for (int t = 0; t < 8; ++t)
        a0[t] = __shfl(alpha0, head_a * 16 + 2 * t + half);
    __builtin_amdgcn_sched_barrier(0);

    float acc0[8];
#pragma unroll
    for (int k = 0; k < 8; ++k) acc0[k] = 0.f;

    // ---- rotate: consume slot, refill it ----
    WAITV(3); CONSUME(0); ISSUE(4);
    WAITV(3); CONSUME(1); ISSUE(5);
    WAITV(3); CONSUME(2); ISSUE(6);
    WAITV(3); CONSUME(3); ISSUE(7);
    WAITV(3); CONSUME(4);
    WAITV(2); CONSUME(5);
    WAITV(1); CONSUME(6);
    WAITV(0); CONSUME(7);

#undef ISSUE
#undef CONSUME
#undef WAITV

#pragma unroll
    for (int k = 0; k < 8; ++k)
        acc0[k] += __shfl_xor(acc0[k], 32);

    const int qb = half * 4;
    *(float4*)(out + (size_t)d0 * 256 + fb + qb) =
        make_float4(acc0[qb], acc0[qb + 1], acc0[qb + 2], acc0[qb + 3]);
}

extern "C" void kernel_launch(void* const* d_in, const int* in_sizes, int n_in,
                              void* d_out, int out_size, void* d_ws, size_t ws_size,
                              hipStream_t stream) {
    const int*   col_ind = (const int*)d_in[1];
    const float* feat    = (const float*)d_in[4];
    const float* W       = (const float*)d_in[5];
    const float* attn_l  = (const float*)d_in[6];
    const float* attn_r  = (const float*)d_in[7];
    float* out = (float*)d_out;

    // ws: Wt 128KB | h_bf 25.6MB | arow 0.8MB | acol 0.8MB
    ushort* Wt   = (ushort*)d_ws;
    ushort* h_bf = Wt + 256 * 256;
    float*  arow = (float*)(h_bf + (size_t)N_NODES * HF);
    float*  acol = arow + (size_t)N_NODES * NH;

    const size_t need = (256 * 256 + (size_t)N_NODES * HF) * 2
                      + (size_t)N_NODES * NH * 4 * 2;
    if (ws_size < need) return;

    cast_wt_kernel<<<16, 256, 0, stream>>>(W, Wt);

    mfma_gemm_kernel<<<(N_NODES + 63) / 64, 256, 0, stream>>>(feat, Wt, attn_l, attn_r,
                                                              h_bf, arow, acol, N_NODES);

    agg_kernel<<<N_NODES / 4, 256, 0, stream>>>(col_ind, h_bf, arow, acol, out);
}